// Round 8
// baseline (180.698 us; speedup 1.0000x reference)
//
#include <hip/hip_runtime.h>
#include <hip/hip_bf16.h>

#define BATCH 2
#define SLEN 2048
#define NH 12
#define DM 768
#define DH 64
#define ROWS (BATCH*SLEN)   // 4096
#define NQKV (3*DM)         // 2304
#define NCHUNK 40           // split-K chunks per bh (q-tile=128, chunk = up to 8 k-tiles)

typedef __attribute__((ext_vector_type(8))) short bf16x8;
typedef __attribute__((ext_vector_type(4))) float f32x4;
typedef unsigned short u16;
typedef unsigned int u32;
typedef __attribute__((ext_vector_type(4))) unsigned short u16x4;
typedef __attribute__((ext_vector_type(8))) unsigned short u16x8;

__device__ __forceinline__ u16 f2b(float f) {
    unsigned int u = __builtin_bit_cast(unsigned int, f);
    unsigned int r = (u + 0x7FFFu + ((u >> 16) & 1u)) >> 16;
    return (u16)r;
}
__device__ __forceinline__ float b2f(u16 v) {
    unsigned int u = ((unsigned int)v) << 16;
    return __builtin_bit_cast(float, u);
}

// async global->LDS, 16B per lane. LDS dest = wave-uniform base + lane*16.
__device__ __forceinline__ void gload16(const u16* g, u16* l) {
    __builtin_amdgcn_global_load_lds(
        (const __attribute__((address_space(1))) unsigned int*)g,
        (__attribute__((address_space(3))) unsigned int*)l,
        16, 0, 0);
}

// ---------------- pack kernels ----------------

__global__ __launch_bounds__(256) void pack_x(const float* __restrict__ x, u16* __restrict__ xb) {
    int i = blockIdx.x * 256 + threadIdx.x;
    const float4* xv = (const float4*)x;
    float4 a = xv[i * 2], b = xv[i * 2 + 1];
    u16x8 o;
    o[0] = f2b(a.x); o[1] = f2b(a.y); o[2] = f2b(a.z); o[3] = f2b(a.w);
    o[4] = f2b(b.x); o[5] = f2b(b.y); o[6] = f2b(b.z); o[7] = f2b(b.w);
    *(u16x8*)(xb + (size_t)i * 8) = o;
}

__global__ __launch_bounds__(256) void pack_wqkv(const float* __restrict__ WQ, const float* __restrict__ WK,
                                                 const float* __restrict__ WV, u16* __restrict__ out) {
    __shared__ u16 L[64 * 72];
    int mt = blockIdx.x, h = blockIdx.y, sel = blockIdx.z;
    const float* W = sel == 0 ? WQ : (sel == 1 ? WK : WV);
    const float* src = W + ((size_t)h * DM + mt * 64) * DH;
    int t = threadIdx.x;
    for (int j = 0; j < 4; j++) {
        int i = t + 256 * j;
        int r = i >> 4, cf = i & 15;
        float4 v = ((const float4*)src)[i];
        u16x4 o; o[0] = f2b(v.x); o[1] = f2b(v.y); o[2] = f2b(v.z); o[3] = f2b(v.w);
        *(u16x4*)&L[r * 72 + cf * 4] = o;
    }
    __syncthreads();
    u16* orow = out + ((size_t)(sel * DM + h * DH)) * DM + mt * 64;
    for (int j = 0; j < 16; j++) {
        int e = t + 256 * j;
        int d = e >> 6, mm = e & 63;
        orow[(size_t)d * DM + mm] = L[mm * 72 + d];
    }
}

__global__ __launch_bounds__(256) void pack_wo(const float* __restrict__ WO, u16* __restrict__ out) {
    __shared__ u16 L[64 * 72];
    int bi = blockIdx.x, bj = blockIdx.y;
    int t = threadIdx.x;
    for (int j = 0; j < 4; j++) {
        int i = t + 256 * j;
        int r = i >> 4, cf = i & 15;
        float4 v = ((const float4*)(WO + (size_t)(bi * 64 + r) * DM + bj * 64))[cf];
        u16x4 o; o[0] = f2b(v.x); o[1] = f2b(v.y); o[2] = f2b(v.z); o[3] = f2b(v.w);
        *(u16x4*)&L[r * 72 + cf * 4] = o;
    }
    __syncthreads();
    for (int j = 0; j < 16; j++) {
        int e = t + 256 * j;
        int c = e >> 6, r = e & 63;
        out[(size_t)(bj * 64 + c) * DM + bi * 64 + r] = L[r * 72 + c];
    }
}

// ---------------- QKV GEMM (128x128, global_load_lds staging, XOR-swizzled LDS) ----

__global__ __launch_bounds__(256) void gemm_qkv(const u16* __restrict__ A, const u16* __restrict__ Bt,
                                                const float* __restrict__ bQ, const float* __restrict__ bK,
                                                const float* __restrict__ bV,
                                                u16* __restrict__ Qb, u16* __restrict__ Kb, u16* __restrict__ Vb) {
    __shared__ u16 Al[128 * 64];
    __shared__ u16 Bl[128 * 64];
    int t = threadIdx.x;
    int n0 = blockIdx.x * 128, m0 = blockIdx.y * 128;
    int lane = t & 63, w = t >> 6;
    int ln = lane & 15, qd = lane >> 4;
    int wr = (w & 1) * 64, wc = (w >> 1) * 64;
    int srow = lane >> 3, slot = lane & 7;
    f32x4 acc[4][4] = {};

    for (int kt = 0; kt < DM / 64; kt++) {
        __syncthreads();
        for (int j = 0; j < 4; j++) {
            int r = w * 32 + j * 8 + srow;
            int gc = slot ^ (r & 7);
            gload16(A + (size_t)(m0 + r) * DM + kt * 64 + gc * 8, &Al[(w * 32 + j * 8) * 64]);
            gload16(Bt + (size_t)(n0 + r) * DM + kt * 64 + gc * 8, &Bl[(w * 32 + j * 8) * 64]);
        }
        __syncthreads();
        for (int ks = 0; ks < 2; ks++) {
            int sl = ((ks * 4 + qd) ^ (ln & 7)) * 8;
            bf16x8 af[4], bfr[4];
            for (int rt = 0; rt < 4; rt++)
                af[rt] = *(const bf16x8*)&Al[(wr + rt * 16 + ln) * 64 + sl];
            for (int ct = 0; ct < 4; ct++)
                bfr[ct] = *(const bf16x8*)&Bl[(wc + ct * 16 + ln) * 64 + sl];
            for (int rt = 0; rt < 4; rt++)
                for (int ct = 0; ct < 4; ct++)
                    acc[rt][ct] = __builtin_amdgcn_mfma_f32_16x16x32_bf16(af[rt], bfr[ct], acc[rt][ct], 0, 0, 0);
        }
    }
    int sel = n0 / DM;
    if (sel == 2) {
        for (int ct = 0; ct < 4; ct++) {
            int col = n0 - 2 * DM + wc + ct * 16 + ln;
            int hh = col >> 6, dd = col & 63;
            float bv = bV[col];
            for (int rt = 0; rt < 4; rt++) {
                int row = m0 + wr + rt * 16 + qd * 4;
                int bb = row >> 11, ss = row & 2047;
                u16x4 pk;
                for (int r = 0; r < 4; r++) pk[r] = f2b(acc[rt][ct][r] + bv);
                *(u16x4*)&Vb[(((size_t)bb * NH + hh) * DH + dd) * SLEN + ss] = pk;
            }
        }
    } else {
        const float* bias = sel == 0 ? bQ : bK;
        u16* Out = sel == 0 ? Qb : Kb;
        const float qs = sel == 0 ? 0.125f * 1.44269504f : 1.0f;
        for (int ct = 0; ct < 4; ct++) {
            int col = n0 - sel * DM + wc + ct * 16 + ln;
            int hh = col >> 6, dd = col & 63;
            float bv = bias[col];
            for (int rt = 0; rt < 4; rt++) {
                int row = m0 + wr + rt * 16 + qd * 4;
                for (int r = 0; r < 4; r++) {
                    int rg = row + r;
                    int bb = rg >> 11, ss = rg & 2047;
                    Out[(((size_t)bb * NH + hh) * SLEN + ss) * DH + dd] = f2b((acc[rt][ct][r] + bv) * qs);
                }
            }
        }
    }
}

// ---------------- split-K flash attention: q-tile=128, transposed-S, gload16 staging ----
// cid in [0,40): q-tile p (128 rows) split into nc chunks of <=8 k-tiles.
// 4 waves x 32 q-rows (two 16-row fragments A/B per wave).

__device__ __forceinline__ void cid2qc(int cid, int& p, int& c, int& nc) {
    if (cid < 4)       { p = cid;                  c = 0;               nc = 1; }
    else if (cid < 12) { p = 4 + ((cid - 4) >> 1);  c = (cid - 4) & 1;   nc = 2; }
    else if (cid < 24) { p = 8 + (cid - 12) / 3;    c = (cid - 12) % 3;  nc = 3; }
    else               { p = 12 + ((cid - 24) >> 2); c = (cid - 24) & 3; nc = 4; }
}

__global__ __launch_bounds__(256, 4) void attn(const u16* __restrict__ Qb, const u16* __restrict__ Kb,
                                               const u16* __restrict__ Vtg,
                                               u16* __restrict__ Po, float* __restrict__ Plv) {
    __shared__ u16 Kl[64 * 64];          // [k][d], 16B chunks XOR-swizzled
    __shared__ u16 Vt[64 * 64];          // [d][k], swizzled
    __shared__ u16 Pq[4 * 32 * 72];      // wave-private P: [q-local][k], padded
    int cid = blockIdx.x, bh = blockIdx.y;
    int p, c, nc;
    cid2qc(cid, p, c, nc);
    int ntiles = 2 * p + 2;
    int kt0 = c * ntiles / nc, kt1 = (c + 1) * ntiles / nc;
    const u16* Qp = Qb + (size_t)bh * SLEN * DH;
    const u16* Kp = Kb + (size_t)bh * SLEN * DH;
    const u16* Vp = Vtg + (size_t)bh * SLEN * DH;  // [d][s]
    int t = threadIdx.x, lane = t & 63, w = t >> 6;
    int ln = lane & 15, qd = lane >> 4;
    int srow = lane >> 3, slot = lane & 7;
    int qbA = p * 128 + w * 32, qbB = qbA + 16;

    bf16x8 qfA[2], qfB[2];
    for (int ks = 0; ks < 2; ks++) {
        qfA[ks] = *(const bf16x8*)(Qp + (size_t)(qbA + ln) * DH + ks * 32 + qd * 8);
        qfB[ks] = *(const bf16x8*)(Qp + (size_t)(qbB + ln) * DH + ks * 32 + qd * 8);
    }

    float lA = 0.f, lB = 0.f;
    f32x4 oA[4] = {}, oB[4] = {};

    u16* PwA = Pq + w * 32 * 72;
    u16* PwB = PwA + 16 * 72;

    for (int kt = kt0; kt < kt1; kt++) {
        int k0 = kt * 64;
        __syncthreads();
        for (int j = 0; j < 2; j++) {
            int r = w * 16 + j * 8 + srow;
            int gc = slot ^ (r & 7);
            gload16(Kp + (size_t)(k0 + r) * DH + gc * 8, &Kl[(w * 16 + j * 8) * 64]);
            gload16(Vp + (size_t)r * SLEN + k0 + gc * 8, &Vt[(w * 16 + j * 8) * 64]);
        }
        __syncthreads();

        // S^T = K Q^T for both q-fragments, sharing K-fragment loads
        f32x4 sfA[4] = {}, sfB[4] = {};
        for (int ks = 0; ks < 2; ks++) {
            int sl = ((ks * 4 + qd) ^ (ln & 7)) * 8;
            for (int ct = 0; ct < 4; ct++) {
                bf16x8 kf = *(const bf16x8*)&Kl[(ct * 16 + ln) * 64 + sl];
                sfA[ct] = __builtin_amdgcn_mfma_f32_16x16x32_bf16(kf, qfA[ks], sfA[ct], 0, 0, 0);
                sfB[ct] = __builtin_amdgcn_mfma_f32_16x16x32_bf16(kf, qfB[ks], sfB[ct], 0, 0, 0);
            }
        }

        // causal mask per fragment (wave-uniform branch)
        if (kt >= (qbA >> 6)) {
            int qg = qbA + ln;
            for (int ct = 0; ct < 4; ct++)
                for (int r = 0; r < 4; r++) {
                    int kg = k0 + ct * 16 + qd * 4 + r;
                    if (kg > qg) sfA[ct][r] = -1e30f;
                }
        }
        if (kt >= (qbB >> 6)) {
            int qg = qbB + ln;
            for (int ct = 0; ct < 4; ct++)
                for (int r = 0; r < 4; r++) {
                    int kg = k0 + ct * 16 + qd * 4 + r;
                    if (kg > qg) sfB[ct][r] = -1e30f;
                }
        }

        // exp2 + truncate-to-bf16 pack (consistent for P and l)
        float sA = 0.f, sB = 0.f;
        for (int ct = 0; ct < 4; ct++) {
            u32 ea[4], eb[4];
            for (int r = 0; r < 4; r++) {
                float eA = exp2f(sfA[ct][r]);
                float eB = exp2f(sfB[ct][r]);
                ea[r] = __builtin_bit_cast(u32, eA);
                eb[r] = __builtin_bit_cast(u32, eB);
                sA += __builtin_bit_cast(float, ea[r] & 0xFFFF0000u);
                sB += __builtin_bit_cast(float, eb[r] & 0xFFFF0000u);
            }
            uint2 pkA, pkB;
            pkA.x = __builtin_amdgcn_perm(ea[1], ea[0], 0x07060302u);
            pkA.y = __builtin_amdgcn_perm(ea[3], ea[2], 0x07060302u);
            pkB.x = __builtin_amdgcn_perm(eb[1], eb[0], 0x07060302u);
            pkB.y = __builtin_amdgcn_perm(eb[3], eb[2], 0x07060302u);
            *(uint2*)&PwA[ln * 72 + ct * 16 + qd * 4] = pkA;
            *(uint2*)&PwB[ln * 72 + ct * 16 + qd * 4] = pkB;
        }
        lA += sA; lB += sB;

        // Z^T += V^T P^T for both fragments, sharing V-fragment loads
        for (int ks = 0; ks < 2; ks++) {
            int sl = ((ks * 4 + qd) ^ (ln & 7)) * 8;
            bf16x8 pfA = *(const bf16x8*)&PwA[ln * 72 + ks * 32 + qd * 8];
            bf16x8 pfB = *(const bf16x8*)&PwB[ln * 72 + ks * 32 + qd * 8];
            for (int dt = 0; dt < 4; dt++) {
                bf16x8 vf = *(const bf16x8*)&Vt[(dt * 16 + ln) * 64 + sl];
                oA[dt] = __builtin_amdgcn_mfma_f32_16x16x32_bf16(vf, pfA, oA[dt], 0, 0, 0);
                oB[dt] = __builtin_amdgcn_mfma_f32_16x16x32_bf16(vf, pfB, oB[dt], 0, 0, 0);
            }
        }
    }

    lA += __shfl_xor(lA, 16, 64);
    lA += __shfl_xor(lA, 32, 64);
    lB += __shfl_xor(lB, 16, 64);
    lB += __shfl_xor(lB, 32, 64);

    // partial: o bf16 [q-local 128][64 d], l f32 [128]
    size_t pid = (size_t)bh * NCHUNK + cid;
    u16* op = Po + pid * 8192;
    for (int dt = 0; dt < 4; dt++) {
        u16x4 ovA, ovB;
        for (int r = 0; r < 4; r++) { ovA[r] = f2b(oA[dt][r]); ovB[r] = f2b(oB[dt][r]); }
        *(u16x4*)&op[(w * 32 + ln) * 64 + dt * 16 + qd * 4] = ovA;
        *(u16x4*)&op[(w * 32 + 16 + ln) * 64 + dt * 16 + qd * 4] = ovB;
    }
    if (qd == 0) {
        Plv[pid * 128 + w * 32 + ln] = lA;
        Plv[pid * 128 + w * 32 + 16 + ln] = lB;
    }
}

// ---------------- combine partials -> Z bf16 [4096][768] ----------------

__global__ __launch_bounds__(256) void combine(const u16* __restrict__ Po, const float* __restrict__ Plv,
                                               u16* __restrict__ Zb) {
    int p = blockIdx.x, bh = blockIdx.y;
    int b = bh / NH, h = bh % NH;
    int nc, base;
    if (p < 4)       { base = p;                  nc = 1; }
    else if (p < 8)  { base = 4 + (p - 4) * 2;    nc = 2; }
    else if (p < 12) { base = 12 + (p - 8) * 3;   nc = 3; }
    else             { base = 24 + (p - 12) * 4;  nc = 4; }
    int t = threadIdx.x;
    int q = t >> 1, dseg = (t & 1) * 32;

    float acc[32] = {};
    float lsum = 0.f;
    for (int cc = 0; cc < nc; cc++) {
        size_t pid = (size_t)bh * NCHUNK + base + cc;
        lsum += Plv[pid * 128 + q];
        const u16* op = Po + pid * 8192 + q * 64 + dseg;
        for (int j = 0; j < 4; j++) {
            u16x8 v = *(const u16x8*)(op + j * 8);
            for (int e = 0; e < 8; e++)
                acc[j * 8 + e] += b2f(v[e]);
        }
    }
    float inv = 1.0f / lsum;
    u16* Zp = Zb + ((size_t)b * SLEN + p * 128 + q) * DM + h * DH + dseg;
    for (int j = 0; j < 4; j++) {
        u16x8 ov;
        for (int e = 0; e < 8; e++) ov[e] = f2b(acc[j * 8 + e] * inv);
        *(u16x8*)(Zp + j * 8) = ov;
    }
}

// ---------------- output projection (64x96 tile, global_load_lds staging) ----------------

__global__ __launch_bounds__(256) void gemm_proj(const u16* __restrict__ A, const u16* __restrict__ Bt,
                                                 const float* __restrict__ bO, float* __restrict__ out) {
    __shared__ u16 Al[64 * 64];
    __shared__ u16 Bl[96 * 64];
    int t = threadIdx.x;
    int n0 = blockIdx.x * 96, m0 = blockIdx.y * 64;
    int lane = t & 63, w = t >> 6;
    int ln = lane & 15, qd = lane >> 4;
    int wr = (w & 1) * 32, wc = (w >> 1) * 48;
    int srow = lane >> 3, slot = lane & 7;
    f32x4 acc[2][3] = {};

    for (int kt = 0; kt < DM / 64; kt++) {
        __syncthreads();
        for (int j = 0; j < 2; j++) {
            int r = w * 16 + j * 8 + srow;
            int gc = slot ^ (r & 7);
            gload16(A + (size_t)(m0 + r) * DM + kt * 64 + gc * 8, &Al[(w * 16 + j * 8) * 64]);
        }
        for (int j = 0; j < 3; j++) {
            int r = w * 24 + j * 8 + srow;
            int gc = slot ^ (r & 7);
            gload16(Bt + (size_t)(n0 + r) * DM + kt * 64 + gc * 8, &Bl[(w * 24 + j * 8) * 64]);
        }
        __syncthreads();
        for (int ks = 0; ks < 2; ks++) {
            int sl = ((ks * 4 + qd) ^ (ln & 7)) * 8;
            bf16x8 af[2], bfr[3];
            for (int rt = 0; rt < 2; rt++)
                af[rt] = *(const bf16x8*)&Al[(wr + rt * 16 + ln) * 64 + sl];
            for (int ct = 0; ct < 3; ct++)
                bfr[ct] = *(const bf16x8*)&Bl[(wc + ct * 16 + ln) * 64 + sl];
            for (int rt = 0; rt < 2; rt++)
                for (int ct = 0; ct < 3; ct++)
                    acc[rt][ct] = __builtin_amdgcn_mfma_f32_16x16x32_bf16(af[rt], bfr[ct], acc[rt][ct], 0, 0, 0);
        }
    }
    for (int ct = 0; ct < 3; ct++) {
        int col = n0 + wc + ct * 16 + ln;
        float bv = bO[col];
        for (int rt = 0; rt < 2; rt++) {
            int row = m0 + wr + rt * 16 + qd * 4;
            for (int r = 0; r < 4; r++)
                out[(size_t)(row + r) * DM + col] = acc[rt][ct][r] + bv;
        }
    }
}

// ---------------- launch ----------------

extern "C" void kernel_launch(void* const* d_in, const int* in_sizes, int n_in,
                              void* d_out, int out_size, void* d_ws, size_t ws_size,
                              hipStream_t stream) {
    const float* x  = (const float*)d_in[0];
    const float* WQ = (const float*)d_in[1];
    const float* bQ = (const float*)d_in[2];
    const float* WK = (const float*)d_in[3];
    const float* bK = (const float*)d_in[4];
    const float* WV = (const float*)d_in[5];
    const float* bV = (const float*)d_in[6];
    const float* WO = (const float*)d_in[7];
    const float* bO = (const float*)d_in[8];
    float* out = (float*)d_out;

    u16* xb   = (u16*)d_ws;                        // [4096][768]
    u16* wqkv = xb + (size_t)ROWS * DM;            // [2304][768]
    u16* wo   = wqkv + (size_t)NQKV * DM;          // [768][768]
    u16* Qb   = wo + (size_t)DM * DM;
    size_t hsz = (size_t)BATCH * NH * SLEN * DH;
    u16* Kb   = Qb + hsz;
    u16* Vb   = Kb + hsz;                          // V^T [b,h,d,s]
    u16* Zb   = Vb + hsz;                          // [4096][768]
    u16* Po   = Zb + (size_t)ROWS * DM;            // partials o: [24*40][128][64] bf16
    float* Pl = (float*)(Po + (size_t)BATCH * NH * NCHUNK * 8192);

    pack_x<<<ROWS * DM / 2048, 256, 0, stream>>>(x, xb);
    pack_wqkv<<<dim3(12, 12, 3), 256, 0, stream>>>(WQ, WK, WV, wqkv);
    pack_wo<<<dim3(12, 12), 256, 0, stream>>>(WO, wo);
    gemm_qkv<<<dim3(NQKV / 128, ROWS / 128), 256, 0, stream>>>(xb, wqkv, bQ, bK, bV, Qb, Kb, Vb);
    attn<<<dim3(NCHUNK, BATCH * NH), 256, 0, stream>>>(Qb, Kb, Vb, Po, Pl);
    combine<<<dim3(SLEN / 128, BATCH * NH), 256, 0, stream>>>(Po, Pl, Zb);
    gemm_proj<<<dim3(DM / 96, ROWS / 64), 256, 0, stream>>>(Zb, wo, bO, out);
}